// Round 1
// baseline (446.054 us; speedup 1.0000x reference)
//
#include <hip/hip_runtime.h>
#include <hip/hip_bf16.h>
#include <stdint.h>

// ---------------------------------------------------------------------------
// PropagationRWKV: LN -> (k,v,r) GEMM -> channel-decay scan -> y GEMM -> out
// B=8, N=16384, C=256. M = 131072 rows.
// bf16 MFMA (16x16x32) for all GEMMs; scan in fp32.
// ---------------------------------------------------------------------------

typedef __attribute__((ext_vector_type(8))) short short8;
typedef __attribute__((ext_vector_type(4))) float f32x4;

static __device__ __forceinline__ unsigned short f2bf(float f) {
  __hip_bfloat16 h = __float2bfloat16(f);
  return *reinterpret_cast<unsigned short*>(&h);
}
static __device__ __forceinline__ float bf2f(unsigned short u) {
  unsigned int v = ((unsigned int)u) << 16;
  float f;
  __builtin_memcpy(&f, &v, 4);
  return f;
}

// ---------------------------------------------------------------------------
// Kernel 1: LayerNorm fp32 -> bf16.  One wave per row (C=256, float4/lane).
// ---------------------------------------------------------------------------
__global__ void ln_kernel(const float* __restrict__ x,
                          const float* __restrict__ w,
                          const float* __restrict__ b,
                          unsigned short* __restrict__ xn) {
  const int wv = threadIdx.x >> 6;
  const int ln = threadIdx.x & 63;
  const size_t row = (size_t)blockIdx.x * 4 + wv;
  const float4 v = reinterpret_cast<const float4*>(x)[row * 64 + ln];
  float s  = v.x + v.y + v.z + v.w;
  float sq = v.x * v.x + v.y * v.y + v.z * v.z + v.w * v.w;
#pragma unroll
  for (int off = 32; off; off >>= 1) {
    s  += __shfl_xor(s, off, 64);
    sq += __shfl_xor(sq, off, 64);
  }
  const float mu  = s * (1.0f / 256.0f);
  const float var = sq * (1.0f / 256.0f) - mu * mu;
  const float rs  = rsqrtf(var + 1e-5f);
  const float4 w4 = reinterpret_cast<const float4*>(w)[ln];
  const float4 b4 = reinterpret_cast<const float4*>(b)[ln];
  ushort4 o;
  o.x = f2bf((v.x - mu) * rs * w4.x + b4.x);
  o.y = f2bf((v.y - mu) * rs * w4.y + b4.y);
  o.z = f2bf((v.z - mu) * rs * w4.z + b4.z);
  o.w = f2bf((v.w - mu) * rs * w4.w + b4.w);
  reinterpret_cast<ushort4*>(xn)[row * 64 + ln] = o;
}

// ---------------------------------------------------------------------------
// Kernel 2: convert weights fp32 -> bf16. Wkvr = [Wk;Wv;Wr] rows 0..767.
// ---------------------------------------------------------------------------
__global__ void cvt_weights(const float* __restrict__ Wk,
                            const float* __restrict__ Wv,
                            const float* __restrict__ Wr,
                            const float* __restrict__ Wo,
                            unsigned short* __restrict__ Wkvr,
                            unsigned short* __restrict__ Wob) {
  const int idx = blockIdx.x * 256 + threadIdx.x;  // 0 .. 1024*256
  if (idx < 768 * 256) {
    const int r = idx >> 8;
    const int c = idx & 255;
    const float* src = (r < 256) ? Wk : ((r < 512) ? Wv : Wr);
    Wkvr[idx] = f2bf(src[(r & 255) * 256 + c]);
  } else {
    const int j = idx - 768 * 256;
    Wob[j] = f2bf(Wo[j]);
  }
}

// ---------------------------------------------------------------------------
// MFMA GEMM: C[m][n] = sum_k A[m][k] * Bt[n][k]   (A: [M][256] bf16,
// Bt: [Nout][256] bf16 row-major == B-transposed form).
// 128x128 tile / block, 4 waves, each wave 64x64 (4x4 of 16x16x32 MFMA).
// BK=64, XOR-swizzled 16B chunks, global_load_lds width 16.
// EPI 0: split kvr epilogue (bf16, sigmoid on r). EPI 1: fp32 out.
// ---------------------------------------------------------------------------
template <int EPI>
__global__ void gemm_bt(const unsigned short* __restrict__ A,
                        const unsigned short* __restrict__ Bt,
                        unsigned short* __restrict__ kbuf,
                        unsigned short* __restrict__ vbuf,
                        unsigned short* __restrict__ rbuf,
                        float* __restrict__ outf) {
  constexpr int K = 256;
  __shared__ unsigned short Als[128][64];  // 16 KiB, swizzled 16B chunks
  __shared__ unsigned short Bls[128][64];  // 16 KiB

  const int tid = threadIdx.x;
  const int wv = tid >> 6;
  const int ln = tid & 63;
  const int bm0 = blockIdx.x * 128;
  const int bn0 = blockIdx.y * 128;
  const int lq = ln >> 4;   // quad 0..3
  const int lm = ln & 15;

  f32x4 acc[4][4];
#pragma unroll
  for (int i = 0; i < 4; ++i)
#pragma unroll
    for (int j = 0; j < 4; ++j) acc[i][j] = (f32x4){0.f, 0.f, 0.f, 0.f};

  const int m0w = (wv >> 1) * 64;
  const int n0w = (wv & 1) * 64;

  const int srow = ln >> 3;              // 0..7 (row within 8-row group)
  const int schunk = (ln & 7) ^ srow;    // swizzled source chunk

  for (int kk0 = 0; kk0 < K; kk0 += 64) {
#pragma unroll
    for (int i = 0; i < 4; ++i) {
      const int rr = wv * 32 + i * 8;    // wave-uniform base row
      const unsigned short* gA = A + (size_t)(bm0 + rr + srow) * K + kk0 + schunk * 8;
      __builtin_amdgcn_global_load_lds(
          (const __attribute__((address_space(1))) void*)gA,
          (__attribute__((address_space(3))) void*)&Als[rr][0], 16, 0, 0);
      const unsigned short* gB = Bt + (size_t)(bn0 + rr + srow) * K + kk0 + schunk * 8;
      __builtin_amdgcn_global_load_lds(
          (const __attribute__((address_space(1))) void*)gB,
          (__attribute__((address_space(3))) void*)&Bls[rr][0], 16, 0, 0);
    }
    __syncthreads();
#pragma unroll
    for (int kk = 0; kk < 64; kk += 32) {
      short8 af[4], bfr[4];
      const int chunk = (kk >> 3) + lq;  // 0..3 or 4..7
#pragma unroll
      for (int t = 0; t < 4; ++t) {
        const int rowa = m0w + t * 16 + lm;
        af[t] = *reinterpret_cast<const short8*>(&Als[rowa][(chunk ^ (rowa & 7)) * 8]);
        const int rowb = n0w + t * 16 + lm;
        bfr[t] = *reinterpret_cast<const short8*>(&Bls[rowb][(chunk ^ (rowb & 7)) * 8]);
      }
#pragma unroll
      for (int mt = 0; mt < 4; ++mt)
#pragma unroll
        for (int nt = 0; nt < 4; ++nt)
          acc[mt][nt] = __builtin_amdgcn_mfma_f32_16x16x32_bf16(
              af[mt], bfr[nt], acc[mt][nt], 0, 0, 0);
    }
    __syncthreads();
  }

  // Epilogue. C/D layout: col = lane&15, row = (lane>>4)*4 + reg.
#pragma unroll
  for (int mt = 0; mt < 4; ++mt) {
#pragma unroll
    for (int nt = 0; nt < 4; ++nt) {
      const int n_g = bn0 + n0w + nt * 16 + lm;
      const int m_base = bm0 + m0w + mt * 16 + lq * 4;
      if (EPI == 0) {
        const int bufi = n_g >> 8;
        const int col = n_g & 255;
        unsigned short* dst = (bufi == 0) ? kbuf : ((bufi == 1) ? vbuf : rbuf);
#pragma unroll
        for (int r = 0; r < 4; ++r) {
          float val = acc[mt][nt][r];
          if (bufi == 2) val = 1.0f / (1.0f + __expf(-val));
          dst[(size_t)(m_base + r) * 256 + col] = f2bf(val);
        }
      } else {
#pragma unroll
        for (int r = 0; r < 4; ++r)
          outf[(size_t)(m_base + r) * 256 + n_g] = acc[mt][nt][r];
      }
    }
  }
}

// ---------------------------------------------------------------------------
// Scan pass A: per (b,chunk) block, per-channel local carry over L=128 steps.
// carry[bch][c] = sum_i d^(L-1-i) * k[i]
// ---------------------------------------------------------------------------
__global__ void scan_carry(const unsigned short* __restrict__ k,
                           const float* __restrict__ td,
                           float* __restrict__ carry) {
  const int bch = blockIdx.x;      // b*128 + chunk
  const int c = threadIdx.x;
  const float d = expf(-fmaxf(td[c], 0.0f));
  const unsigned short* kp = k + (size_t)bch * 128 * 256 + c;
  float s = 0.0f;
#pragma unroll 8
  for (int i = 0; i < 128; ++i) s = s * d + bf2f(kp[(size_t)i * 256]);
  carry[(size_t)bch * 256 + c] = s;
}

// ---------------------------------------------------------------------------
// Scan pass B: exclusive scan of chunk carries (in-place: carry -> carry_in).
// s_in(j+1) = d^L * s_in(j) + carry(j)
// ---------------------------------------------------------------------------
__global__ void scan_chunks(float* __restrict__ carry,
                            const float* __restrict__ td) {
  const int b = blockIdx.x;
  const int c = threadIdx.x;
  const float relu_td = fmaxf(td[c], 0.0f);
  const float dL = expf(-relu_td * 128.0f);
  float s = 0.0f;
  for (int j = 0; j < 128; ++j) {
    const size_t idx = ((size_t)b * 128 + j) * 256 + c;
    const float cj = carry[idx];
    carry[idx] = s;       // exclusive prefix (state entering chunk j)
    s = dL * s + cj;
  }
}

// ---------------------------------------------------------------------------
// Scan pass C: recompute states with carry-in, y = r*(state+v) -> bf16,
// written in-place over k (same index, sequential in-thread: safe).
// ---------------------------------------------------------------------------
__global__ void scan_final(unsigned short* __restrict__ k,
                           const unsigned short* __restrict__ v,
                           const unsigned short* __restrict__ r,
                           const float* __restrict__ carryin,
                           const float* __restrict__ td) {
  const int bch = blockIdx.x;
  const int c = threadIdx.x;
  const float d = expf(-fmaxf(td[c], 0.0f));
  const size_t base = (size_t)bch * 128 * 256 + c;
  float s = carryin[(size_t)bch * 256 + c];
#pragma unroll 4
  for (int i = 0; i < 128; ++i) {
    const size_t off = base + (size_t)i * 256;
    s = s * d + bf2f(k[off]);
    const float y = bf2f(r[off]) * (s + bf2f(v[off]));
    k[off] = f2bf(y);
  }
}

// ---------------------------------------------------------------------------
extern "C" void kernel_launch(void* const* d_in, const int* in_sizes, int n_in,
                              void* d_out, int out_size, void* d_ws, size_t ws_size,
                              hipStream_t stream) {
  const float* x   = (const float*)d_in[0];
  const float* td  = (const float*)d_in[1];
  const float* Wk  = (const float*)d_in[2];
  const float* Wv  = (const float*)d_in[3];
  const float* Wr  = (const float*)d_in[4];
  const float* Wo  = (const float*)d_in[5];
  const float* lnw = (const float*)d_in[6];
  const float* lnb = (const float*)d_in[7];
  float* out = (float*)d_out;

  const int Bsz = 8, C = 256;
  const size_t M = 131072;  // B*N

  char* ws = (char*)d_ws;
  size_t off = 0;
  auto alloc = [&](size_t bytes) -> char* {
    char* p = ws + off;
    off += (bytes + 255) & ~(size_t)255;
    return p;
  };
  unsigned short* xn   = (unsigned short*)alloc(M * C * 2);
  unsigned short* kbuf = (unsigned short*)alloc(M * C * 2);  // later holds y
  unsigned short* vbuf = (unsigned short*)alloc(M * C * 2);
  unsigned short* rbuf = (unsigned short*)alloc(M * C * 2);
  unsigned short* Wkvr = (unsigned short*)alloc(768 * 256 * 2);
  unsigned short* Wob  = (unsigned short*)alloc(256 * 256 * 2);
  float* carry = (float*)alloc((size_t)Bsz * 128 * C * 4);
  (void)ws_size; (void)in_sizes; (void)n_in; (void)out_size;

  cvt_weights<<<dim3(1024), dim3(256), 0, stream>>>(Wk, Wv, Wr, Wo, Wkvr, Wob);
  ln_kernel<<<dim3((unsigned)(M / 4)), dim3(256), 0, stream>>>(x, lnw, lnb, xn);
  gemm_bt<0><<<dim3((unsigned)(M / 128), 6), dim3(256), 0, stream>>>(
      xn, Wkvr, kbuf, vbuf, rbuf, nullptr);
  scan_carry<<<dim3(Bsz * 128), dim3(256), 0, stream>>>(kbuf, td, carry);
  scan_chunks<<<dim3(Bsz), dim3(256), 0, stream>>>(carry, td);
  scan_final<<<dim3(Bsz * 128), dim3(256), 0, stream>>>(kbuf, vbuf, rbuf, carry, td);
  gemm_bt<1><<<dim3((unsigned)(M / 128), 2), dim3(256), 0, stream>>>(
      kbuf, Wob, nullptr, nullptr, nullptr, out);
}

// Round 2
// 440.262 us; speedup vs baseline: 1.0132x; 1.0132x over previous
//
#include <hip/hip_runtime.h>
#include <hip/hip_bf16.h>
#include <stdint.h>

// ---------------------------------------------------------------------------
// PropagationRWKV: LN -> (k,v,r) GEMM -> channel-decay scan -> y GEMM -> out
// B=8, N=16384, C=256. M = 131072 rows.
// bf16 MFMA (16x16x32); Ct trick (swap operands) for contiguous-n epilogue.
// ---------------------------------------------------------------------------

typedef __attribute__((ext_vector_type(8))) short short8;
typedef __attribute__((ext_vector_type(4))) float f32x4;

static __device__ __forceinline__ unsigned short f2bf(float f) {
  __hip_bfloat16 h = __float2bfloat16(f);
  return *reinterpret_cast<unsigned short*>(&h);
}
static __device__ __forceinline__ float bf2f(unsigned short u) {
  unsigned int v = ((unsigned int)u) << 16;
  float f;
  __builtin_memcpy(&f, &v, 4);
  return f;
}

// ---------------------------------------------------------------------------
// Kernel 1: LayerNorm fp32 -> bf16.  One wave per row (C=256, float4/lane).
// ---------------------------------------------------------------------------
__global__ void ln_kernel(const float* __restrict__ x,
                          const float* __restrict__ w,
                          const float* __restrict__ b,
                          unsigned short* __restrict__ xn) {
  const int wv = threadIdx.x >> 6;
  const int ln = threadIdx.x & 63;
  const size_t row = (size_t)blockIdx.x * 4 + wv;
  const float4 v = reinterpret_cast<const float4*>(x)[row * 64 + ln];
  float s  = v.x + v.y + v.z + v.w;
  float sq = v.x * v.x + v.y * v.y + v.z * v.z + v.w * v.w;
#pragma unroll
  for (int off = 32; off; off >>= 1) {
    s  += __shfl_xor(s, off, 64);
    sq += __shfl_xor(sq, off, 64);
  }
  const float mu  = s * (1.0f / 256.0f);
  const float var = sq * (1.0f / 256.0f) - mu * mu;
  const float rs  = rsqrtf(var + 1e-5f);
  const float4 w4 = reinterpret_cast<const float4*>(w)[ln];
  const float4 b4 = reinterpret_cast<const float4*>(b)[ln];
  ushort4 o;
  o.x = f2bf((v.x - mu) * rs * w4.x + b4.x);
  o.y = f2bf((v.y - mu) * rs * w4.y + b4.y);
  o.z = f2bf((v.z - mu) * rs * w4.z + b4.z);
  o.w = f2bf((v.w - mu) * rs * w4.w + b4.w);
  reinterpret_cast<ushort4*>(xn)[row * 64 + ln] = o;
}

// ---------------------------------------------------------------------------
// Kernel 2: convert weights fp32 -> bf16. Wkvr = [Wk;Wv;Wr] rows 0..767.
// ---------------------------------------------------------------------------
__global__ void cvt_weights(const float* __restrict__ Wk,
                            const float* __restrict__ Wv,
                            const float* __restrict__ Wr,
                            const float* __restrict__ Wo,
                            unsigned short* __restrict__ Wkvr,
                            unsigned short* __restrict__ Wob) {
  const int idx = blockIdx.x * 256 + threadIdx.x;  // 0 .. 1024*256
  if (idx < 768 * 256) {
    const int r = idx >> 8;
    const int c = idx & 255;
    const float* src = (r < 256) ? Wk : ((r < 512) ? Wv : Wr);
    Wkvr[idx] = f2bf(src[(r & 255) * 256 + c]);
  } else {
    const int j = idx - 768 * 256;
    Wob[j] = f2bf(Wo[j]);
  }
}

// ---------------------------------------------------------------------------
// MFMA GEMM: C[m][n] = sum_k A[m][k] * Bt[n][k].
// 128x128 tile / block, 4 waves, 64x64 per wave (4x4 of 16x16x32 MFMA).
// Operand-SWAPPED mfma (computes Ct fragments): lane holds 4 CONSECUTIVE n
// per acc -> 8B bf16 / 16B fp32 stores.
// Grid is 1D, n-fastest (id%NY) so n-slices of one m-tile share A in L2.
// EPI 0: split k/v/sigmoid(r) bf16 epilogue. EPI 1: fp32 out.
// ---------------------------------------------------------------------------
template <int EPI, int NY>
__global__ void gemm_bt(const unsigned short* __restrict__ A,
                        const unsigned short* __restrict__ Bt,
                        unsigned short* __restrict__ kbuf,
                        unsigned short* __restrict__ vbuf,
                        unsigned short* __restrict__ rbuf,
                        float* __restrict__ outf) {
  constexpr int K = 256;
  __shared__ unsigned short Als[128][64];  // 16 KiB, swizzled 16B chunks
  __shared__ unsigned short Bls[128][64];  // 16 KiB

  const int tid = threadIdx.x;
  const int wv = tid >> 6;
  const int ln = tid & 63;
  const int bid = blockIdx.x;
  const int bm0 = (bid / NY) * 128;
  const int bn0 = (bid % NY) * 128;
  const int lq = ln >> 4;   // quad 0..3
  const int lm = ln & 15;

  f32x4 acc[4][4];
#pragma unroll
  for (int i = 0; i < 4; ++i)
#pragma unroll
    for (int j = 0; j < 4; ++j) acc[i][j] = (f32x4){0.f, 0.f, 0.f, 0.f};

  const int m0w = (wv >> 1) * 64;
  const int n0w = (wv & 1) * 64;

  const int srow = ln >> 3;              // 0..7 (row within 8-row group)
  const int schunk = (ln & 7) ^ srow;    // swizzled source chunk

  for (int kk0 = 0; kk0 < K; kk0 += 64) {
#pragma unroll
    for (int i = 0; i < 4; ++i) {
      const int rr = wv * 32 + i * 8;    // wave-uniform base row
      const unsigned short* gA = A + (size_t)(bm0 + rr + srow) * K + kk0 + schunk * 8;
      __builtin_amdgcn_global_load_lds(
          (const __attribute__((address_space(1))) void*)gA,
          (__attribute__((address_space(3))) void*)&Als[rr][0], 16, 0, 0);
      const unsigned short* gB = Bt + (size_t)(bn0 + rr + srow) * K + kk0 + schunk * 8;
      __builtin_amdgcn_global_load_lds(
          (const __attribute__((address_space(1))) void*)gB,
          (__attribute__((address_space(3))) void*)&Bls[rr][0], 16, 0, 0);
    }
    __syncthreads();
#pragma unroll
    for (int kk = 0; kk < 64; kk += 32) {
      short8 af[4], bfr[4];
      const int chunk = (kk >> 3) + lq;  // 0..3 or 4..7
#pragma unroll
      for (int t = 0; t < 4; ++t) {
        const int rowa = m0w + t * 16 + lm;
        af[t] = *reinterpret_cast<const short8*>(&Als[rowa][(chunk ^ (rowa & 7)) * 8]);
        const int rowb = n0w + t * 16 + lm;
        bfr[t] = *reinterpret_cast<const short8*>(&Bls[rowb][(chunk ^ (rowb & 7)) * 8]);
      }
      // Swapped operands: computes Ct. Lane holds col=m (lm), rows = 4
      // consecutive n (lq*4 + reg).
#pragma unroll
      for (int mt = 0; mt < 4; ++mt)
#pragma unroll
        for (int nt = 0; nt < 4; ++nt)
          acc[mt][nt] = __builtin_amdgcn_mfma_f32_16x16x32_bf16(
              bfr[nt], af[mt], acc[mt][nt], 0, 0, 0);
    }
    __syncthreads();
  }

  // Epilogue (Ct layout): m = ...+lm, n_base = ...+lq*4, regs span n.
#pragma unroll
  for (int mt = 0; mt < 4; ++mt) {
    const int m_g = bm0 + m0w + mt * 16 + lm;
#pragma unroll
    for (int nt = 0; nt < 4; ++nt) {
      const int n_base = bn0 + n0w + nt * 16 + lq * 4;
      f32x4 a = acc[mt][nt];
      if (EPI == 0) {
        const int bufi = n_base >> 8;   // uniform within a 16-wide nt tile
        const int col = n_base & 255;
        unsigned short* dst = (bufi == 0) ? kbuf : ((bufi == 1) ? vbuf : rbuf);
        if (bufi == 2) {
#pragma unroll
          for (int r = 0; r < 4; ++r) a[r] = 1.0f / (1.0f + __expf(-a[r]));
        }
        ushort4 pk;
        pk.x = f2bf(a[0]); pk.y = f2bf(a[1]); pk.z = f2bf(a[2]); pk.w = f2bf(a[3]);
        *reinterpret_cast<ushort4*>(&dst[(size_t)m_g * 256 + col]) = pk;
      } else {
        float4 o = make_float4(a[0], a[1], a[2], a[3]);
        *reinterpret_cast<float4*>(&outf[(size_t)m_g * 256 + n_base]) = o;
      }
    }
  }
}

// ---------------------------------------------------------------------------
// Scan decomposition: NCHUNK=256 chunks of L=64 per batch.
// Pass A: per-chunk local carry. Thread = (bch, 8-channel group), 16B loads.
// ---------------------------------------------------------------------------
__global__ void scan_carry(const unsigned short* __restrict__ k,
                           const float* __restrict__ td,
                           float* __restrict__ carry) {
  const int lane32 = threadIdx.x & 31;
  const int sub = threadIdx.x >> 5;               // 8 chunks per block
  const int bch = blockIdx.x * 8 + sub;           // 0 .. 2047
  const int c0 = lane32 * 8;
  float d[8], s[8];
#pragma unroll
  for (int j = 0; j < 8; ++j) {
    d[j] = expf(-fmaxf(td[c0 + j], 0.0f));
    s[j] = 0.0f;
  }
  const unsigned short* kp = k + (size_t)bch * 64 * 256 + c0;
#pragma unroll 4
  for (int i = 0; i < 64; ++i) {
    short8 kv = *reinterpret_cast<const short8*>(kp + (size_t)i * 256);
#pragma unroll
    for (int j = 0; j < 8; ++j) s[j] = s[j] * d[j] + bf2f((unsigned short)kv[j]);
  }
  float4* cp = reinterpret_cast<float4*>(carry + (size_t)bch * 256 + c0);
  cp[0] = make_float4(s[0], s[1], s[2], s[3]);
  cp[1] = make_float4(s[4], s[5], s[6], s[7]);
}

// ---------------------------------------------------------------------------
// Pass B: exclusive scan of chunk carries per batch (in-place), 8-wide
// load prefetch to break the serial latency chain.
// ---------------------------------------------------------------------------
__global__ void scan_chunks(float* __restrict__ carry,
                            const float* __restrict__ td) {
  const int b = blockIdx.x;
  const int c = threadIdx.x;
  const float dL = expf(-fmaxf(td[c], 0.0f) * 64.0f);
  float s = 0.0f;
  float* base = carry + (size_t)b * 256 * 256 + c;  // 256 chunks, stride 256
  for (int j0 = 0; j0 < 256; j0 += 8) {
    float buf[8];
#pragma unroll
    for (int t = 0; t < 8; ++t) buf[t] = base[(size_t)(j0 + t) * 256];
#pragma unroll
    for (int t = 0; t < 8; ++t) {
      base[(size_t)(j0 + t) * 256] = s;
      s = dL * s + buf[t];
    }
  }
}

// ---------------------------------------------------------------------------
// Pass C: recompute states with carry-in, y = r*(state+v) -> bf16 over k.
// ---------------------------------------------------------------------------
__global__ void scan_final(unsigned short* __restrict__ k,
                           const unsigned short* __restrict__ v,
                           const unsigned short* __restrict__ r,
                           const float* __restrict__ carryin,
                           const float* __restrict__ td) {
  const int lane32 = threadIdx.x & 31;
  const int sub = threadIdx.x >> 5;
  const int bch = blockIdx.x * 8 + sub;
  const int c0 = lane32 * 8;
  float d[8], s[8];
  const float4* ci = reinterpret_cast<const float4*>(carryin + (size_t)bch * 256 + c0);
  float4 c0v = ci[0], c1v = ci[1];
  s[0] = c0v.x; s[1] = c0v.y; s[2] = c0v.z; s[3] = c0v.w;
  s[4] = c1v.x; s[5] = c1v.y; s[6] = c1v.z; s[7] = c1v.w;
#pragma unroll
  for (int j = 0; j < 8; ++j) d[j] = expf(-fmaxf(td[c0 + j], 0.0f));
  const size_t base = (size_t)bch * 64 * 256 + c0;
#pragma unroll 2
  for (int i = 0; i < 64; ++i) {
    const size_t off = base + (size_t)i * 256;
    short8 kv = *reinterpret_cast<const short8*>(k + off);
    short8 vv = *reinterpret_cast<const short8*>(v + off);
    short8 rv = *reinterpret_cast<const short8*>(r + off);
    short8 y;
#pragma unroll
    for (int j = 0; j < 8; ++j) {
      s[j] = s[j] * d[j] + bf2f((unsigned short)kv[j]);
      const float yj = bf2f((unsigned short)rv[j]) * (s[j] + bf2f((unsigned short)vv[j]));
      y[j] = (short)f2bf(yj);
    }
    *reinterpret_cast<short8*>(k + off) = y;
  }
}

// ---------------------------------------------------------------------------
extern "C" void kernel_launch(void* const* d_in, const int* in_sizes, int n_in,
                              void* d_out, int out_size, void* d_ws, size_t ws_size,
                              hipStream_t stream) {
  const float* x   = (const float*)d_in[0];
  const float* td  = (const float*)d_in[1];
  const float* Wk  = (const float*)d_in[2];
  const float* Wv  = (const float*)d_in[3];
  const float* Wr  = (const float*)d_in[4];
  const float* Wo  = (const float*)d_in[5];
  const float* lnw = (const float*)d_in[6];
  const float* lnb = (const float*)d_in[7];
  float* out = (float*)d_out;

  const int Bsz = 8, C = 256;
  const size_t M = 131072;  // B*N

  char* ws = (char*)d_ws;
  size_t off = 0;
  auto alloc = [&](size_t bytes) -> char* {
    char* p = ws + off;
    off += (bytes + 255) & ~(size_t)255;
    return p;
  };
  unsigned short* xn   = (unsigned short*)alloc(M * C * 2);
  unsigned short* kbuf = (unsigned short*)alloc(M * C * 2);  // later holds y
  unsigned short* vbuf = (unsigned short*)alloc(M * C * 2);
  unsigned short* rbuf = (unsigned short*)alloc(M * C * 2);
  unsigned short* Wkvr = (unsigned short*)alloc(768 * 256 * 2);
  unsigned short* Wob  = (unsigned short*)alloc(256 * 256 * 2);
  float* carry = (float*)alloc((size_t)Bsz * 256 * C * 4);
  (void)ws_size; (void)in_sizes; (void)n_in; (void)out_size;

  cvt_weights<<<dim3(1024), dim3(256), 0, stream>>>(Wk, Wv, Wr, Wo, Wkvr, Wob);
  ln_kernel<<<dim3((unsigned)(M / 4)), dim3(256), 0, stream>>>(x, lnw, lnb, xn);
  gemm_bt<0, 6><<<dim3(1024 * 6), dim3(256), 0, stream>>>(
      xn, Wkvr, kbuf, vbuf, rbuf, nullptr);
  scan_carry<<<dim3(256), dim3(256), 0, stream>>>(kbuf, td, carry);
  scan_chunks<<<dim3(Bsz), dim3(256), 0, stream>>>(carry, td);
  scan_final<<<dim3(256), dim3(256), 0, stream>>>(kbuf, vbuf, rbuf, carry, td);
  gemm_bt<1, 2><<<dim3(1024 * 2), dim3(256), 0, stream>>>(
      kbuf, Wob, nullptr, nullptr, nullptr, out);
}